// Round 4
// baseline (68.582 us; speedup 1.0000x reference)
//
#include <hip/hip_runtime.h>

#define NPTS 768
#define TPB  256

// out[a,i] = sum_{b,r,j} exp(-gamma_r (d(a,b)-mu_r)^2)/sqrt(n) * W[r,i,j] * f[b,j]
// One block per output row a (768 blocks = 3/CU, all co-resident).
// Factor: T[r,j] = sum_b rbf[b,r] * f[b,j]; out[i] = sum_{r,j} W[r,i,j] T[r,j].
__global__ __launch_bounds__(TPB) void rbf_conv_kernel(
        const float* __restrict__ feat,   // [768][16] f32
        const float* __restrict__ geom,   // [768][3]  f32
        const float* __restrict__ Wp,     // [8][16][16] f32
        const float* __restrict__ mup,    // [8] f32
        const float* __restrict__ gmp,    // [8] f32
        const int*   __restrict__ nn,     // [1] int32
        float* __restrict__ outp)         // [768][16] f32
{
    // zone: phase1/2 = rbf rows (12 floats / 48 B stride, two aligned float4)
    //       phase3   = Tp[64][132] f32 partials (8448 floats <= 9216)
    __shared__ __align__(16) float zone[NPTS * 12];   // 36864 B
    __shared__ float Wl[2048];                        // W as [r][j][i], 8192 B
    __shared__ float Pp2[256];                        // 1024 B   (total ~45 KB -> 3 blocks/CU)

    const int t = threadIdx.x;
    const int a = blockIdx.x;

    // ---- stage W transposed: Wl[r*256 + j*16 + i] = W[r][i][j] (once, overlaps phase 1) ----
    for (int s = t; s < 2048; s += TPB) {
        const int r = s >> 8, rem = s & 255, i = rem >> 4, j = rem & 15;
        Wl[r * 256 + j * 16 + i] = Wp[s];
    }

    const float ax = geom[a * 3 + 0];   // block-uniform -> scalar loads
    const float ay = geom[a * 3 + 1];
    const float az = geom[a * 3 + 2];
    float muv[8], ngv[8];
#pragma unroll
    for (int r = 0; r < 8; ++r) { muv[r] = mup[r]; ngv[r] = -gmp[r]; }
    const float lrn = __logf(rsqrtf((float)nn[0]));   // fold 1/sqrt(n) into exponent

    // ---- phase 1: rbf[b][0..7] = exp(-gamma*(d-mu)^2 + lrn), straight from global geom ----
#pragma unroll
    for (int k = 0; k < 3; ++k) {
        const int b = t + (k << 8);
        const float dx = geom[b * 3 + 0] - ax;
        const float dy = geom[b * 3 + 1] - ay;
        const float dz = geom[b * 3 + 2] - az;
        const float d = sqrtf(fmaf(dx, dx, fmaf(dy, dy, fmaf(dz, dz, 1e-9f))));
        float e[8];
#pragma unroll
        for (int r = 0; r < 8; ++r) {
            const float u = d - muv[r];
            e[r] = __expf(fmaf(ngv[r] * u, u, lrn));
        }
        *(float4*)(zone + b * 12 + 0) = make_float4(e[0], e[1], e[2], e[3]);
        *(float4*)(zone + b * 12 + 4) = make_float4(e[4], e[5], e[6], e[7]);
    }
    __syncthreads();                                   // B1

    // ---- phase 2: T-partials. thread (g = t>>2, jq = t&3) owns j = jq*4..jq*4+3 ----
    const int jq = t & 3;
    const int g  = t >> 2;
    float acc[8][4];
#pragma unroll
    for (int r = 0; r < 8; ++r)
#pragma unroll
        for (int jj = 0; jj < 4; ++jj) acc[r][jj] = 0.f;

    const float4* feat4 = (const float4*)feat;         // [768][4] float4
#pragma unroll
    for (int k = 0; k < 12; ++k) {
        const int b = g + (k << 6);
        const float4 ra = *(const float4*)(zone + b * 12 + 0);   // rbf r=0..3 (4-lane bcast)
        const float4 rb = *(const float4*)(zone + b * 12 + 4);   // rbf r=4..7
        const float4 fv = feat4[b * 4 + jq];                     // coalesced 1 KB/wave
        const float rr[8] = { ra.x, ra.y, ra.z, ra.w, rb.x, rb.y, rb.z, rb.w };
        const float fj[4] = { fv.x, fv.y, fv.z, fv.w };
#pragma unroll
        for (int r = 0; r < 8; ++r)
#pragma unroll
            for (int jj = 0; jj < 4; ++jj)
                acc[r][jj] = fmaf(rr[r], fj[jj], acc[r][jj]);
    }
    __syncthreads();                                   // B2 (zone reads done before overwrite)

    // ---- phase 3: partials Tp[g][rj], row stride 132 floats ----
    float* Tp = zone;
#pragma unroll
    for (int r = 0; r < 8; ++r)
        *(float4*)(Tp + g * 132 + r * 16 + jq * 4) =
            make_float4(acc[r][0], acc[r][1], acc[r][2], acc[r][3]);
    __syncthreads();                                   // B3

    // ---- reduction on ALL 256 threads: t -> (rj = t&127, h = t>>7), 32 gg each ----
    {
        const int rj = t & 127, h = t >> 7;
        const float* base = Tp + (h << 5) * 132 + rj;  // 64 consecutive dwords/wave: conflict-free
        float s = 0.f;
#pragma unroll
        for (int gg = 0; gg < 32; ++gg) s += base[gg * 132];
        Pp2[t] = s;
    }
    __syncthreads();                                   // B4

    // ---- epilogue: single wave, shuffle finish. out[i] = sum_{r,j} W[r,i,j] T[r,j] ----
    if (t < 64) {
        const int i = t & 15, q = t >> 4;
        float s = 0.f;
#pragma unroll
        for (int m = 0; m < 32; ++m) {
            const int rj = (q << 5) + m;
            const int r = rj >> 4, j = rj & 15;
            const float Tv = Pp2[rj] + Pp2[rj + 128];
            s = fmaf(Wl[r * 256 + j * 16 + i], Tv, s);
        }
        s += __shfl_xor(s, 16);
        s += __shfl_xor(s, 32);
        if (t < 16) outp[a * 16 + t] = s;
    }
}

extern "C" void kernel_launch(void* const* d_in, const int* in_sizes, int n_in,
                              void* d_out, int out_size, void* d_ws, size_t ws_size,
                              hipStream_t stream) {
    const float* feat = (const float*)d_in[0];
    const float* geom = (const float*)d_in[1];
    const float* Wp   = (const float*)d_in[2];
    const float* mup  = (const float*)d_in[3];
    const float* gmp  = (const float*)d_in[4];
    const int*   nn   = (const int*)d_in[5];
    float* outp = (float*)d_out;
    rbf_conv_kernel<<<dim3(NPTS), dim3(TPB), 0, stream>>>(feat, geom, Wp, mup, gmp, nn, outp);
}